// Round 7
// baseline (185.155 us; speedup 1.0000x reference)
//
#include <hip/hip_runtime.h>

// KANStressPredictor v13: zero-intermediary direct stride-48 kernel (probe).
// v12 post-mortem: MLP levers (depth-2 prefetch, 8-chunk blocks, nt-stores)
// changed NOTHING (59->62us). Four structures (v6 block-LDS / v7 shuffle /
// v9,v12 wave-LDS) all pinned 59-65us with no pipe >51%; harness fill does
// 6.8 TB/s and m13's float4 copy 6.29 TB/s -> not a machine/mixed-R/W wall.
// Common to all four (and absent from a copy): an interposed transform stage
// (LDS+lgkmcnt fences or shuffles) and VGPR 20-28 = compiler built a
// non-pipelined loop serializing vmcnt waits against the transform.
// v13 removes the intermediary entirely: each lane loads its 4 triplets
// DIRECTLY from global at 48B stride (3 consecutive dwordx4/lane). A wave's
// 3 loads touch the same contiguous 3KB / 24 cache lines: zero over-fetch,
// clean stream from L2's view. No LDS, no fences, no shuffles. Explicit A/B
// dual body puts 6 loads in flight before first use (forces pipelining,
// VGPR ~50-60). Closest-possible-to-copy structure with compute folded in.
// Pre-committed read: ~35-45us -> kernel-stall theory confirmed, iterate;
// 58-63us again -> five structures pinned = environment wall, ROOFLINE.
// Math (verified, absmax 0.0078 vs 0.0248 thr): 5 trans/triplet via
// log2(lam1) = log2(det) - log2(lam0).
// NOTE: __builtin_log2f/exp2f, NOT __log2f/__exp2f (glibc host-pass collision).

typedef unsigned int u32;

__device__ __forceinline__ void compute3(float s0, float s1, float s2,
                                         float ki0, float ki1,
                                         float& o0, float& o1, float& o2) {
    const float c00 = __builtin_fmaf(2.0f, s0, 1.0f);
    const float c11 = __builtin_fmaf(2.0f, s1, 1.0f);
    const float c01 = s2;
    const float det = c00 * c11 - c01 * c01;          // det(C) > 0 (SPD)
    const float l2det = __builtin_log2f(det);
    const float mean = 0.5f * (c00 + c11);
    const float diff = 0.5f * (c00 - c11);
    const float rad  = __builtin_sqrtf(__builtin_fmaf(diff, diff, c01 * c01));
    const float l2lam0 = __builtin_log2f(mean - rad); // no cancellation: mean>=1
    const float l2a = -0.16666666667f * l2det;        // log2(det^(-1/6))
    o0 = __builtin_exp2f(ki0 * __builtin_fmaf(0.5f, l2lam0, l2a));
    // log2(lam1) = l2det - l2lam0
    o1 = __builtin_exp2f(ki0 * __builtin_fmaf(-0.5f, l2lam0,
                                  __builtin_fmaf(0.5f, l2det, l2a)));
    o2 = (0.34657359028f * l2det) * ki1;              // log(J)=0.5*ln2*l2det
}

// one lane-triple: 3 consecutive float4 = 4 whole triplets, load->compute->store
__device__ __forceinline__ void do_triple(const float4* __restrict__ in4,
                                          float4* __restrict__ out4,
                                          u32 i, float ki0, float ki1) {
    const float4 x = in4[3u * i];
    const float4 y = in4[3u * i + 1];
    const float4 z = in4[3u * i + 2];
    float o0,o1,o2,o3,o4,o5,o6,o7,o8,o9,oa,ob;
    compute3(x.x, x.y, x.z, ki0, ki1, o0, o1, o2);
    compute3(x.w, y.x, y.y, ki0, ki1, o3, o4, o5);
    compute3(y.z, y.w, z.x, ki0, ki1, o6, o7, o8);
    compute3(z.y, z.z, z.w, ki0, ki1, o9, oa, ob);
    out4[3u * i]     = make_float4(o0, o1, o2, o3);
    out4[3u * i + 1] = make_float4(o4, o5, o6, o7);
    out4[3u * i + 2] = make_float4(o8, o9, oa, ob);
}

constexpr int TPB = 256;

__global__ __launch_bounds__(TPB) void kan_v13_direct(
    const float* __restrict__ strain,
    const float* __restrict__ ki0p,
    const float* __restrict__ ki1p,
    float* __restrict__ out,
    int nfloat_i)
{
    const float ki0 = ki0p[0];
    const float ki1 = ki1p[0];
    const u32 nfloat = (u32)nfloat_i;
    const u32 nquads = nfloat >> 2;
    const u32 ntriple = nquads / 3u;   // lane-triples (4 triplets each)
    const u32 t = threadIdx.x;
    const float4* __restrict__ in4 = (const float4*)strain;
    float4* __restrict__ out4 = (float4*)out;
    const u32 gs = gridDim.x * (u32)TPB;

    // A/B dual body: 6 loads issued before any use -> forced MLP/pipelining
    u32 iA = blockIdx.x * (u32)TPB + t;
    for (; iA + gs < ntriple; iA += 2u * gs) {
        const u32 iB = iA + gs;
        const float4 ax = in4[3u * iA],     ay = in4[3u * iA + 1], az = in4[3u * iA + 2];
        const float4 bx = in4[3u * iB],     by = in4[3u * iB + 1], bz = in4[3u * iB + 2];

        float o0,o1,o2,o3,o4,o5,o6,o7,o8,o9,oa,ob;
        compute3(ax.x, ax.y, ax.z, ki0, ki1, o0, o1, o2);
        compute3(ax.w, ay.x, ay.y, ki0, ki1, o3, o4, o5);
        compute3(ay.z, ay.w, az.x, ki0, ki1, o6, o7, o8);
        compute3(az.y, az.z, az.w, ki0, ki1, o9, oa, ob);
        out4[3u * iA]     = make_float4(o0, o1, o2, o3);
        out4[3u * iA + 1] = make_float4(o4, o5, o6, o7);
        out4[3u * iA + 2] = make_float4(o8, o9, oa, ob);

        compute3(bx.x, bx.y, bx.z, ki0, ki1, o0, o1, o2);
        compute3(bx.w, by.x, by.y, ki0, ki1, o3, o4, o5);
        compute3(by.z, by.w, bz.x, ki0, ki1, o6, o7, o8);
        compute3(bz.y, bz.z, bz.w, ki0, ki1, o9, oa, ob);
        out4[3u * iB]     = make_float4(o0, o1, o2, o3);
        out4[3u * iB + 1] = make_float4(o4, o5, o6, o7);
        out4[3u * iB + 2] = make_float4(o8, o9, oa, ob);
    }
    for (; iA < ntriple; iA += gs) {
        do_triple(in4, out4, iA, ki0, ki1);
    }

    // scalar tail: triplets past the float4-triple region (empty for bench shape)
    const u32 ntrip = nfloat / 3u;
    const u32 t0 = ntriple * 4u;
    for (u32 e = t0 + blockIdx.x * (u32)TPB + t; e < ntrip; e += gs) {
        float x0, x1, x2;
        compute3(strain[3 * e], strain[3 * e + 1], strain[3 * e + 2],
                 ki0, ki1, x0, x1, x2);
        out[3 * e]     = x0;
        out[3 * e + 1] = x1;
        out[3 * e + 2] = x2;
    }
}

extern "C" void kernel_launch(void* const* d_in, const int* in_sizes, int n_in,
                              void* d_out, int out_size, void* d_ws, size_t ws_size,
                              hipStream_t stream) {
    const float* strain = (const float*)d_in[0];
    const float* ki0p   = (const float*)d_in[1];
    const float* ki1p   = (const float*)d_in[2];
    float* out = (float*)d_out;

    const int nfloat = in_sizes[0];
    const u32 nquads = ((u32)nfloat) >> 2;
    const u32 ntriple = nquads / 3u;
    u32 blocks = (ntriple + (u32)TPB - 1u) / (u32)TPB;  // one pass...
    if (blocks > 2048u) blocks = 2048u;                 // 8 blocks/CU, grid-stride
    if (blocks < 1u) blocks = 1u;

    kan_v13_direct<<<(int)blocks, TPB, 0, stream>>>(strain, ki0p, ki1p, out, nfloat);
}